// Round 10
// baseline (258.606 us; speedup 1.0000x reference)
//
#include <hip/hip_runtime.h>
#include <math.h>

// Spherical harmonics edge attributes, lmax=2.
// Outputs (concat flat): edge_vec [E,3] | edge_length [E] | edge_sh [E,9]
//
// Round-10: wave-private LDS staging, ZERO barriers, 3-stage prefetch.
// Counter evidence:
//  R7: 108us, WRITE exact 162.5MB w/ regular out_sh stores, VALU 3.8%
//  R8: +pipeline -> 103us; nt scalar out_sh -> WRITE 258MB (amplification)
//  R9: +LDS-staged out_sh v4f flush (2 barriers/tile) -> ~88us (below top-5)
//  Floor: ~200MB HBM traffic ~ 31us. Still stall-bound (occ 55%, VALU 4%).
// Changes:
//  - Each WAVE owns a private 3KB LDS slice; stages out_vec AND out_sh for
//    its 64-edge chunk, flushes as full-line nt v4f. Within-wave LDS
//    write->read needs only lgkmcnt (no barrier): __syncthreads ELIMINATED.
//  - Grid-stride over 64-edge chunks with 3-stage prefetch per wave:
//    idx(c+2) | gathers+shift(c+1) | compute+stage+flush(c).
//    FIFO vmcnt: compute waits only its own (oldest) loads.
//  - out_len: direct nt scalar store (stride-4 = full 256B/wave coverage).
//  - 1 edge/lane/chunk -> small register state -> higher occupancy.
// Pure function of input buffers: deterministic by construction.

#define SQRT3 1.7320508075688772f
#define SQRT5 2.2360679774997896f

typedef float v4f __attribute__((ext_vector_type(4)));

#define NTL(p)    __builtin_nontemporal_load(p)
#define NTS(v, p) __builtin_nontemporal_store((v), (p))

__global__ __launch_bounds__(256) void sh_edge_kernel(
    const float*  __restrict__ pos,       // [N,3]
    const int*    __restrict__ edge_index,// [2,E]
    const float*  __restrict__ shift,     // [E,3]
    float* __restrict__ out_vec,          // [E,3]
    float* __restrict__ out_len,          // [E]
    float* __restrict__ out_sh,           // [E,9]
    int n_edges)
{
    // per-wave slice: vec 192 floats + sh 576 floats = 768 floats = 3KB
    __shared__ float s_buf[4][768];

    const int lane = threadIdx.x & 63;
    const int wid  = threadIdx.x >> 6;
    float* s_vec = s_buf[wid];          // 192 floats
    float* s_sh  = s_buf[wid] + 192;    // 576 floats

    const int n_chunks = (n_edges + 63) >> 6;
    const int wstride  = gridDim.x << 2;          // waves in grid

    int c1 = (blockIdx.x << 2) + wid;             // current chunk
    if (c1 >= n_chunks) return;

    // ---------------- prologue: fill pipeline ----------------
    int  e1 = (c1 << 6) + lane;
    bool v1 = e1 < n_edges;
    float ax1=0,ay1=0,az1=0,bx1=0,by1=0,bz1=0,hx1=0,hy1=0,hz1=0;
    {
        int s=0,d=0;
        if (v1) { s = NTL(&edge_index[e1]); d = NTL(&edge_index[n_edges + e1]); }
        if (v1) {
            const float* p = pos + 3 * (size_t)s; ax1=p[0]; ay1=p[1]; az1=p[2];
            const float* q = pos + 3 * (size_t)d; bx1=q[0]; by1=q[1]; bz1=q[2];
            const float* sp = shift + 3 * (size_t)e1;
            hx1=NTL(&sp[0]); hy1=NTL(&sp[1]); hz1=NTL(&sp[2]);
        }
    }
    int  c2 = c1 + wstride;
    int  s2 = 0, d2 = 0;
    bool v2 = false;
    if (c2 < n_chunks) {
        const int e2 = (c2 << 6) + lane;
        v2 = e2 < n_edges;
        if (v2) { s2 = NTL(&edge_index[e2]); d2 = NTL(&edge_index[n_edges + e2]); }
    }

    // ---------------- steady-state loop (no barriers) ----------------
    while (true) {
        const bool have_next = (c2 < n_chunks);

        // ---- stage B: issue gathers + shift for c2 (idx prefetched) ----
        float xax=0,xay=0,xaz=0,xbx=0,xby=0,xbz=0,xhx=0,xhy=0,xhz=0;
        if (have_next && v2) {
            const int e2 = (c2 << 6) + lane;
            const float* p = pos + 3 * (size_t)s2; xax=p[0]; xay=p[1]; xaz=p[2];
            const float* q = pos + 3 * (size_t)d2; xbx=q[0]; xby=q[1]; xbz=q[2];
            const float* sp = shift + 3 * (size_t)e2;
            xhx=NTL(&sp[0]); xhy=NTL(&sp[1]); xhz=NTL(&sp[2]);
        }

        // ---- stage A: issue idx for c3 ----
        const int c3 = c2 + wstride;
        int s3=0, d3=0; bool v3=false;
        if (c3 < n_chunks) {
            const int e3 = (c3 << 6) + lane;
            v3 = e3 < n_edges;
            if (v3) { s3 = NTL(&edge_index[e3]); d3 = NTL(&edge_index[n_edges + e3]); }
        }

        // ---- stage C: compute + stage + flush chunk c1 ----
        const int base = c1 << 6;
        const bool full = (base + 64 <= n_edges);
        if (full) {
            const float x = bx1 - ax1 - hx1;
            const float y = by1 - ay1 - hy1;
            const float z = bz1 - az1 - hz1;
            s_vec[3*lane + 0] = x;
            s_vec[3*lane + 1] = y;
            s_vec[3*lane + 2] = z;
            const float sq = x*x + y*y + z*z;
            const float r  = rsqrtf(sq);
            NTS(sq * r, &out_len[e1]);                 // stride-4: full coverage
            const float nx = x*r, ny = y*r, nz = z*r;
            const float x2 = nx*nx, y2 = ny*ny, z2 = nz*nz;
            float* o = s_sh + 9*lane;
            o[0] = 1.0f;
            o[1] = SQRT3 * nx;
            o[2] = SQRT3 * ny;
            o[3] = SQRT3 * nz;
            o[4] = SQRT5 * SQRT3 * nx * nz;
            o[5] = SQRT5 * SQRT3 * nx * ny;
            o[6] = SQRT5 * (y2 - 0.5f * (x2 + z2));
            o[7] = SQRT5 * SQRT3 * ny * nz;
            o[8] = SQRT5 * 0.5f * SQRT3 * (z2 - x2);

            // wave-private flush (lgkmcnt ordering only, no barrier):
            v4f* gv = reinterpret_cast<v4f*>(out_vec + 3 * (size_t)base);
            const v4f* lv = reinterpret_cast<const v4f*>(s_vec);   // 48 v4f
            if (lane < 48) NTS(lv[lane], &gv[lane]);

            v4f* gs = reinterpret_cast<v4f*>(out_sh + 9 * (size_t)base);
            const v4f* ls = reinterpret_cast<const v4f*>(s_sh);    // 144 v4f
            NTS(ls[lane],      &gs[lane]);
            NTS(ls[lane + 64], &gs[lane + 64]);
            if (lane < 16) NTS(ls[lane + 128], &gs[lane + 128]);
        } else if (v1) {
            // partial tail chunk: direct scalar stores
            const float x = bx1 - ax1 - hx1;
            const float y = by1 - ay1 - hy1;
            const float z = bz1 - az1 - hz1;
            float* ov = out_vec + 3 * (size_t)e1;
            ov[0] = x; ov[1] = y; ov[2] = z;
            const float sq = x*x + y*y + z*z;
            const float r  = rsqrtf(sq);
            out_len[e1] = sq * r;
            const float nx = x*r, ny = y*r, nz = z*r;
            const float x2 = nx*nx, y2 = ny*ny, z2 = nz*nz;
            float* o = out_sh + 9 * (size_t)e1;
            o[0] = 1.0f;
            o[1] = SQRT3 * nx;
            o[2] = SQRT3 * ny;
            o[3] = SQRT3 * nz;
            o[4] = SQRT5 * SQRT3 * nx * nz;
            o[5] = SQRT5 * SQRT3 * nx * ny;
            o[6] = SQRT5 * (y2 - 0.5f * (x2 + z2));
            o[7] = SQRT5 * SQRT3 * ny * nz;
            o[8] = SQRT5 * 0.5f * SQRT3 * (z2 - x2);
        }

        if (!have_next) break;

        // ---- rotate pipeline ----
        c1 = c2; e1 = (c1 << 6) + lane; v1 = v2;
        ax1=xax; ay1=xay; az1=xaz; bx1=xbx; by1=xby; bz1=xbz;
        hx1=xhx; hy1=xhy; hz1=xhz;
        c2 = c3; s2 = s3; d2 = d3; v2 = v3;
    }
}

extern "C" void kernel_launch(void* const* d_in, const int* in_sizes, int n_in,
                              void* d_out, int out_size, void* d_ws, size_t ws_size,
                              hipStream_t stream) {
    const float* pos        = (const float*)d_in[0];
    const int*   edge_index = (const int*)d_in[1];
    const float* shift      = (const float*)d_in[2];

    const int n_edges = in_sizes[2] / 3;   // shift is [E,3]

    float* out_vec = (float*)d_out;                        // [E,3]
    float* out_len = (float*)d_out + 3 * (size_t)n_edges;  // [E]
    float* out_sh  = (float*)d_out + 4 * (size_t)n_edges;  // [E,9]

    const int n_chunks = (n_edges + 63) / 64;
    int blocks = (n_chunks + 3) / 4;
    if (blocks > 2048) blocks = 2048;      // ~8 blocks/CU, grid-stride waves
    sh_edge_kernel<<<blocks, 256, 0, stream>>>(
        pos, edge_index, shift, out_vec, out_len, out_sh, n_edges);
}

// Round 11
// 255.172 us; speedup vs baseline: 1.0135x; 1.0135x over previous
//
#include <hip/hip_runtime.h>
#include <math.h>

// Spherical harmonics edge attributes, lmax=2.
// Outputs (concat flat): edge_vec [E,3] | edge_length [E] | edge_sh [E,9]
//
// Round-11: R9 structure, single change: ALL output stores REGULAR (not nt).
// Evidence trail:
//  R7: regular scalar stride-36 out_sh stores -> WRITE exact 162.5MB
//      (L2 write-combines partial lines perfectly); 108us, no pipeline.
//  R8: +3-stage pipeline -> 103us; nt scalar out_sh -> WRITE 258MB
//      (nt does NOT write-combine partial lines).
//  R9: LDS-staged out_sh, full-line nt v4f flush -> ~88us (below top-5).
//  R10: zero-barrier variant ~= R9 -> barriers exonerated.
//  Harness fill: 6.5 TB/s with REGULAR stores; our nt rounds all measured
//      ~2.2-2.9 TB/s effective -> hypothesis: nt path caps drain rate.
//  FETCH=36MB (inputs L3-resident) -> pos L2-eviction risk is only an L3
//      hit (~400cy), already covered by the 1-tile-deep gather pipeline.
// Change: every output store plain (L2-allocating, write-combining).
//  - out_sh: LDS-staged, regular v4f flush (full lines via L2)
//  - out_vec: regular scalar stores (stride-12; R7 proved exact combining)
//  - out_len: regular scalar store (stride-4, full coverage)
// Loads unchanged: idx/shift nt (single-use streams), pos regular.
// Pure function of input buffers: deterministic by construction.

#define SQRT3 1.7320508075688772f
#define SQRT5 2.2360679774997896f

typedef float v4f __attribute__((ext_vector_type(4)));

#define NTL(p)    __builtin_nontemporal_load(p)

__global__ __launch_bounds__(256) void sh_edge_kernel(
    const float*  __restrict__ pos,       // [N,3]
    const int*    __restrict__ edge_index,// [2,E]
    const float*  __restrict__ shift,     // [E,3]
    float* __restrict__ out_vec,          // [E,3]
    float* __restrict__ out_len,          // [E]
    float* __restrict__ out_sh,           // [E,9]
    int n_edges)
{
    __shared__ float s_sh[4608];          // 512 edges x 9 = 18.4 KB
    const int tid     = threadIdx.x;
    const int n_tiles = (n_edges + 511) >> 9;
    const int tstride = gridDim.x;

    int t_cur = blockIdx.x;
    if (t_cur >= n_tiles) return;

    // ---- pipeline registers ----
    float aAx=0,aAy=0,aAz=0,bAx=0,bAy=0,bAz=0,hAx=0,hAy=0,hAz=0;
    float aBx=0,aBy=0,aBz=0,bBx=0,bBy=0,bBz=0,hBx=0,hBy=0,hBz=0;
    int nAs=0,nAd=0,nBs=0,nBd=0;

    // ---------------- prologue ----------------
    {
        const int base = t_cur << 9;
        const int eA = base + tid, eB = eA + 256;
        int sA=0,dA=0,sB=0,dB=0;
        const bool vA = eA < n_edges, vB = eB < n_edges;
        if (vA) { sA = NTL(&edge_index[eA]); dA = NTL(&edge_index[n_edges + eA]); }
        if (vB) { sB = NTL(&edge_index[eB]); dB = NTL(&edge_index[n_edges + eB]); }
        if (vA) {
            const float* p = pos + 3 * (size_t)sA; aAx=p[0]; aAy=p[1]; aAz=p[2];
            const float* q = pos + 3 * (size_t)dA; bAx=q[0]; bAy=q[1]; bAz=q[2];
            const float* sp = shift + 3 * (size_t)eA;
            hAx=NTL(&sp[0]); hAy=NTL(&sp[1]); hAz=NTL(&sp[2]);
        }
        if (vB) {
            const float* p = pos + 3 * (size_t)sB; aBx=p[0]; aBy=p[1]; aBz=p[2];
            const float* q = pos + 3 * (size_t)dB; bBx=q[0]; bBy=q[1]; bBz=q[2];
            const float* sp = shift + 3 * (size_t)eB;
            hBx=NTL(&sp[0]); hBy=NTL(&sp[1]); hBz=NTL(&sp[2]);
        }
    }
    int t_nxt = t_cur + tstride;
    if (t_nxt < n_tiles) {
        const int base = t_nxt << 9;
        const int eA = base + tid, eB = eA + 256;
        if (eA < n_edges) { nAs = NTL(&edge_index[eA]); nAd = NTL(&edge_index[n_edges + eA]); }
        if (eB < n_edges) { nBs = NTL(&edge_index[eB]); nBd = NTL(&edge_index[n_edges + eB]); }
    }

    // ---------------- steady-state loop ----------------
    while (true) {
        const int  base      = t_cur << 9;
        const bool have_next = (t_nxt < n_tiles);

        // ---- stage B: issue gathers + shift for t_nxt ----
        float xaAx=0,xaAy=0,xaAz=0,xbAx=0,xbAy=0,xbAz=0,xhAx=0,xhAy=0,xhAz=0;
        float xaBx=0,xaBy=0,xaBz=0,xbBx=0,xbBy=0,xbBz=0,xhBx=0,xhBy=0,xhBz=0;
        if (have_next) {
            const int nb = t_nxt << 9;
            const int eA = nb + tid, eB = eA + 256;
            if (eA < n_edges) {
                const float* p = pos + 3 * (size_t)nAs; xaAx=p[0]; xaAy=p[1]; xaAz=p[2];
                const float* q = pos + 3 * (size_t)nAd; xbAx=q[0]; xbAy=q[1]; xbAz=q[2];
                const float* sp = shift + 3 * (size_t)eA;
                xhAx=NTL(&sp[0]); xhAy=NTL(&sp[1]); xhAz=NTL(&sp[2]);
            }
            if (eB < n_edges) {
                const float* p = pos + 3 * (size_t)nBs; xaBx=p[0]; xaBy=p[1]; xaBz=p[2];
                const float* q = pos + 3 * (size_t)nBd; xbBx=q[0]; xbBy=q[1]; xbBz=q[2];
                const float* sp = shift + 3 * (size_t)eB;
                xhBx=NTL(&sp[0]); xhBy=NTL(&sp[1]); xhBz=NTL(&sp[2]);
            }
        }

        // ---- stage A: issue idx for t_nxt2 ----
        const int t_n2 = t_nxt + tstride;
        int mAs=0,mAd=0,mBs=0,mBd=0;
        if (t_n2 < n_tiles) {
            const int nb = t_n2 << 9;
            const int eA = nb + tid, eB = eA + 256;
            if (eA < n_edges) { mAs = NTL(&edge_index[eA]); mAd = NTL(&edge_index[n_edges + eA]); }
            if (eB < n_edges) { mBs = NTL(&edge_index[eB]); mBd = NTL(&edge_index[n_edges + eB]); }
        }

        // ---- stage C: compute t_cur (regular stores: L2 write-combines) ----
        const int nblk = min(512, n_edges - base);
#define EDGE_COMPUTE(k, AX,AY,AZ, BX,BY,BZ, HX,HY,HZ)                     \
        {                                                                 \
            const int e = base + (k);                                     \
            const float x = (BX) - (AX) - (HX);                           \
            const float y = (BY) - (AY) - (HY);                           \
            const float z = (BZ) - (AZ) - (HZ);                           \
            float* ov = out_vec + 3 * (size_t)e;                          \
            ov[0] = x; ov[1] = y; ov[2] = z;                              \
            const float sq = x*x + y*y + z*z;                             \
            const float r  = rsqrtf(sq);                                  \
            out_len[e] = sq * r;                                          \
            const float nx = x*r, ny = y*r, nz = z*r;                     \
            const float x2 = nx*nx, y2 = ny*ny, z2 = nz*nz;               \
            float* o = s_sh + 9 * (k);                                    \
            o[0] = 1.0f;                                                  \
            o[1] = SQRT3 * nx;                                            \
            o[2] = SQRT3 * ny;                                            \
            o[3] = SQRT3 * nz;                                            \
            o[4] = SQRT5 * SQRT3 * nx * nz;                               \
            o[5] = SQRT5 * SQRT3 * nx * ny;                               \
            o[6] = SQRT5 * (y2 - 0.5f * (x2 + z2));                       \
            o[7] = SQRT5 * SQRT3 * ny * nz;                               \
            o[8] = SQRT5 * 0.5f * SQRT3 * (z2 - x2);                      \
        }
        if (tid < nblk)
            EDGE_COMPUTE(tid,       aAx,aAy,aAz, bAx,bAy,bAz, hAx,hAy,hAz);
        if (tid + 256 < nblk)
            EDGE_COMPUTE(tid + 256, aBx,aBy,aBz, bBx,bBy,bBz, hBx,hBy,hBz);
#undef EDGE_COMPUTE
        __syncthreads();

        // ---- flush s_sh -> out_sh (regular full-line v4f) ----
        if (nblk == 512) {
            v4f* gs = reinterpret_cast<v4f*>(out_sh + 9 * (size_t)base);
            const v4f* ls = reinterpret_cast<const v4f*>(s_sh);  // 1152 v4f
            gs[tid]       = ls[tid];
            gs[tid + 256] = ls[tid + 256];
            gs[tid + 512] = ls[tid + 512];
            gs[tid + 768] = ls[tid + 768];
            if (tid < 128)
                gs[tid + 1024] = ls[tid + 1024];
        } else {
            for (int i = tid; i < 9 * nblk; i += 256)
                out_sh[9 * (size_t)base + i] = s_sh[i];
        }

        if (!have_next) break;
        __syncthreads();   // WAR: next iteration rewrites s_sh

        // ---- rotate pipeline ----
        t_cur = t_nxt; t_nxt = t_n2;
        aAx=xaAx; aAy=xaAy; aAz=xaAz; bAx=xbAx; bAy=xbAy; bAz=xbAz;
        hAx=xhAx; hAy=xhAy; hAz=xhAz;
        aBx=xaBx; aBy=xaBy; aBz=xaBz; bBx=xbBx; bBy=xbBy; bBz=xbBz;
        hBx=xhBx; hBy=xhBy; hBz=xhBz;
        nAs=mAs; nAd=mAd; nBs=mBs; nBd=mBd;
    }
}

extern "C" void kernel_launch(void* const* d_in, const int* in_sizes, int n_in,
                              void* d_out, int out_size, void* d_ws, size_t ws_size,
                              hipStream_t stream) {
    const float* pos        = (const float*)d_in[0];
    const int*   edge_index = (const int*)d_in[1];
    const float* shift      = (const float*)d_in[2];

    const int n_edges = in_sizes[2] / 3;   // shift is [E,3]

    float* out_vec = (float*)d_out;                        // [E,3]
    float* out_len = (float*)d_out + 3 * (size_t)n_edges;  // [E]
    float* out_sh  = (float*)d_out + 4 * (size_t)n_edges;  // [E,9]

    const int n_tiles = (n_edges + 511) / 512;
    int blocks = n_tiles < 2048 ? n_tiles : 2048;  // persistent grid-stride
    sh_edge_kernel<<<blocks, 256, 0, stream>>>(
        pos, edge_index, shift, out_vec, out_len, out_sh, n_edges);
}